// Round 16
// baseline (158.945 us; speedup 1.0000x reference)
//
#include <hip/hip_runtime.h>
#include <hip/hip_bf16.h>

typedef unsigned short u16;
typedef __attribute__((ext_vector_type(8))) short bf16x8;
typedef __attribute__((ext_vector_type(4))) float f32x4;
typedef __attribute__((ext_vector_type(4))) int i32x4;

#define AS1 __attribute__((address_space(1)))
#define AS3 __attribute__((address_space(3)))

// ---- constants for this problem ----
#define Bx 8
#define Tt 2048
#define Dd 1024
#define Nn 256
#define Mm (Bx*Tt)          // 16384
#define CHAINS (Bx*Nn)      // 2048
#define NCH 32
#define TC 64               // T / NCH
#define NCOMB 1792          // 768 (abc) + 1024 (d)

#define WS_NEED 105644032u

#define CVT_BLOCKS (Mm*Dd/8/256)   // 8192 (8 floats per thread)
#define PACK_BLOCKS (32*32*5)      // 5120

#define VMCNT3 asm volatile("s_waitcnt vmcnt(3)" ::: "memory")
#define VMCNT0 asm volatile("s_waitcnt vmcnt(0)" ::: "memory")
#define LGKM0  asm volatile("s_waitcnt lgkmcnt(0)" ::: "memory")
#define BARR   __builtin_amdgcn_s_barrier()
#define SCHEDB __builtin_amdgcn_sched_barrier(0)

__device__ __forceinline__ u16 f2bf(float f) {
  union { float f; unsigned u; } v; v.f = f;
  unsigned u = v.u;
  u += 0x7fffu + ((u >> 16) & 1u);   // RNE
  return (u16)(u >> 16);
}

__device__ __forceinline__ float bf2f(u16 h) {
  union { unsigned u; float f; } v; v.u = ((unsigned)h) << 16;
  return v.f;
}

__device__ __forceinline__ void gload_lds16(const void* g, void* l) {
  __builtin_amdgcn_global_load_lds((AS1 void*)(g), (AS3 void*)(l), 16, 0, 0);
}

// inline-asm LDS read: opaque to compiler alias tracking (no auto vmcnt(0)
// insertion against outstanding global_load_lds). Correctness owned by the
// explicit vmcnt ledger + barriers in the K-loop.
__device__ __forceinline__ bf16x8 ds_read_b128_asm(unsigned byte_addr) {
  i32x4 r;
  asm volatile("ds_read_b128 %0, %1" : "=v"(r) : "v"(byte_addr));
  return __builtin_bit_cast(bf16x8, r);
}

// ---------------- fused prep: x fp32->bf16 + weight pack ----------------
__global__ void prep_kernel(const float* __restrict__ x, u16* __restrict__ xb,
                            const float* __restrict__ Wa, const float* __restrict__ Wb,
                            const float* __restrict__ Wc, const float* __restrict__ Wd,
                            const float* __restrict__ Wy,
                            u16* __restrict__ Wcomb, u16* __restrict__ Wyt) {
  const int bid = blockIdx.x;
  if (bid < CVT_BLOCKS) {
    int i = bid * blockDim.x + threadIdx.x;
    #pragma unroll
    for (int j = 0; j < 2; ++j) {
      float4 v = ((const float4*)x)[2*i + j];
      unsigned lo = (unsigned)f2bf(v.x) | ((unsigned)f2bf(v.y) << 16);
      unsigned hi = (unsigned)f2bf(v.z) | ((unsigned)f2bf(v.w) << 16);
      ((uint2*)xb)[2*i + j] = make_uint2(lo, hi);
    }
    return;
  }
  __shared__ float tile[32][33];
  const int pid = bid - CVT_BLOCKS;
  const int z = pid >> 10;          // /1024
  const int rem = pid & 1023;
  const int bx = rem & 31, by = rem >> 5;
  const float* src; u16* dst; int R, C, dld;
  if (z < 3)       { src = (z==0?Wa:(z==1?Wb:Wc)); dst = Wcomb + (size_t)z*256*1024; R=1024; C=256;  dld=1024; }
  else if (z == 3) { src = Wd; dst = Wcomb + (size_t)768*1024; R=1024; C=1024; dld=1024; }
  else             { src = Wy; dst = Wyt; R=256;  C=1024; dld=256;  }
  int c0 = bx * 32, r0 = by * 32;
  if (c0 >= C || r0 >= R) return;
  int tx = threadIdx.x & 31, ty = threadIdx.x >> 5;   // 32x8
  #pragma unroll
  for (int i = 0; i < 32; i += 8)
    tile[ty + i][tx] = src[(size_t)(r0 + ty + i)*C + (c0 + tx)];
  __syncthreads();
  #pragma unroll
  for (int i = 0; i < 32; i += 8) {
    int c = c0 + ty + i, r = r0 + tx;
    dst[(size_t)c*dld + r] = f2bf(tile[tx][ty + i]);
  }
}

// ---------------- GEMM: C[M,*] = A[M,K] * Bt[*,K]^T, bf16 in, fp32 acc ----
// r13 residency (BM=256 x BN=128, 8 waves 4x2, acc[4][4], 2 blocks/CU,
// 16 waves/CU) + BK=32 DOUBLE-BUFFER with inline-asm ds_read_b128 so the
// compiler cannot insert alias-conservative vmcnt(0) before LDS reads.
// LDS: A [2][256][32] (32KB) + B [2][128][32] (16KB) = 48KB -> 2 blocks/CU.
// Ledger: stage(t) = 3 gload_lds/thread. Prologue stages t0,t1 (6 in
// flight), vmcnt(3) -> t0 ready. Iter t: asm ds_read x8 from buf(t&1);
// lgkmcnt(0); sched_barrier; 16 MFMA (setprio); barrier (all reads done);
// stage(t+2) into buf(t&1); vmcnt(3) -> t+1 landed (issued a full iter
// ago); barrier. vmcnt never drains to 0 in steady state.
// Swizzle (64B rows, 4x16B slots): key=(row>>1)&3; stage source slot
// (tid-slot)^key, ds_read slot kq^key. 8-lane phases hit 8 distinct
// 16B-quads -> conflict-free.
// EPI 0: coln<768 -> abc (bf16) sigmoid/+bias/fast-tanh; else d -> bf16 dtmp.
// EPI 2: outO = acc + b0[col] + dtmp[row,col]
template<int EPI>
__global__ __launch_bounds__(512, 4) void gemm_bt_kernel(
    const u16* __restrict__ A, const u16* __restrict__ Bt, int K, int gx,
    u16* __restrict__ outA, float* __restrict__ outO, u16* __restrict__ dtmp,
    const float* __restrict__ b0, const float* __restrict__ b1,
    const float* __restrict__ b2, const float* __restrict__ b3) {
  __shared__ u16 ldsA[2*256*32];   // 32 KiB
  __shared__ u16 ldsB[2*128*32];   // 16 KiB
  const int tid = threadIdx.x;
  const int lane = tid & 63, wid = tid >> 6;
  const int wm = wid >> 1, wn = wid & 1;

  // XCD-chunked bijective swizzle (gridDim.x % 8 == 0), n-fastest in chunk
  const int h = blockIdx.x;
  const int id = (h & 7) * (gridDim.x >> 3) + (h >> 3);
  const int mt = id / gx, nt = id % gx;
  const int m0 = mt * 256, n0 = nt * 128;
  const int NT = K >> 5;

  f32x4 acc[4][4] = {};

  // staging: wave w covers rows w*16..w*16+15 of a 128-row unit;
  // lane: row = wid*16 + (lane>>2), slot = lane&3, source slot = slot^key(row)
  const int srow = wid*16 + (lane >> 2);          // 0..127
  const int sslot = (lane & 3) ^ ((srow >> 1) & 3);

  auto stage = [&](int buf, int t) {
    const int k0 = t << 5;
    #pragma unroll
    for (int u = 0; u < 2; ++u)   // A: 256 rows = 2 units of 128
      gload_lds16(A + (size_t)(m0 + u*128 + srow)*K + k0 + sslot*8,
                  ldsA + buf*8192 + u*4096 + wid*512);
    gload_lds16(Bt + (size_t)(n0 + srow)*K + k0 + sslot*8,
                ldsB + buf*4096 + wid*512);
  };

  // fragment-read mapping: row = base + lr, k-slot kq, swizzled slot kq^key
  const int lr = lane & 15, kq = lane >> 4;
  const int key = (lr >> 1) & 3;                  // (row>>1)&3, base%8==0
  const unsigned lbA = (unsigned)(size_t)(AS3 const u16*)ldsA;
  const unsigned lbB = (unsigned)(size_t)(AS3 const u16*)ldsB;
  const unsigned aoff = (unsigned)((wm*64 + lr)*64 + ((kq ^ key) << 4));
  const unsigned boff = (unsigned)((wn*64 + lr)*64 + ((kq ^ key) << 4));

  // prologue: stage tiles 0,1; wait tile 0
  stage(0, 0);
  stage(1, (NT > 1) ? 1 : 0);
  VMCNT3;
  BARR; SCHEDB;

  for (int t = 0; t < NT; ++t) {
    const int buf = t & 1;
    const unsigned ab = lbA + buf*16384 + aoff;
    const unsigned bb = lbB + buf*8192  + boff;

    bf16x8 af[4], bfr[4];
    #pragma unroll
    for (int mi = 0; mi < 4; ++mi) af[mi]  = ds_read_b128_asm(ab + mi*1024);
    #pragma unroll
    for (int ni = 0; ni < 4; ++ni) bfr[ni] = ds_read_b128_asm(bb + ni*1024);
    LGKM0; SCHEDB;                       // rule #18: fence MFMA hoisting

    __builtin_amdgcn_s_setprio(1);
    #pragma unroll
    for (int mi = 0; mi < 4; ++mi)
      #pragma unroll
      for (int ni = 0; ni < 4; ++ni)
        acc[mi][ni] = __builtin_amdgcn_mfma_f32_16x16x32_bf16(af[mi], bfr[ni], acc[mi][ni], 0, 0, 0);
    __builtin_amdgcn_s_setprio(0);
    SCHEDB;
    BARR; SCHEDB;                        // all waves done reading buf(t)

    if (t + 2 < NT) {
      stage(buf, t + 2);                 // overwrite freed buffer
      VMCNT3;                            // t+1 (issued last iter) landed
    } else {
      VMCNT0;                            // tail: drain remaining
    }
    SCHEDB;
    BARR; SCHEDB;                        // t+1 visible to all waves
  }

  // epilogue: C/D layout col=lane&15, row=(lane>>4)*4+r  [m89-verified]
  const int crow = m0 + wm*64 + (lane >> 4)*4;
  const int ccol = wn*64 + (lane & 15);
  #pragma unroll
  for (int mi = 0; mi < 4; ++mi) {
    #pragma unroll
    for (int ni = 0; ni < 4; ++ni) {
      int coln = n0 + ccol + ni*16;
      #pragma unroll
      for (int r = 0; r < 4; ++r) {
        int row = crow + mi*16 + r;
        float v = acc[mi][ni][r];
        if (EPI == 0) {
          if (coln < 768) {
            int seg = coln >> 8, cn = coln & 255;
            if (seg == 0)      v = 1.f / (1.f + __expf(-(v + b0[cn])));
            else if (seg == 1) v = v + b1[cn];
            else {             // fast tanh: 1 - 2/(1+e^{2x})
              float e = __expf(2.f*(v + b2[cn]));
              v = 1.f - 2.f/(1.f + e);
            }
            outA[(size_t)row*768 + coln] = f2bf(v);
          } else {
            int col = coln - 768;
            if (dtmp) dtmp[(size_t)row*1024 + col] = f2bf(v + b3[col]);
            else      outO[(size_t)row*1024 + col] = v + b3[col];
          }
        } else {
          const size_t o = (size_t)row*1024 + coln;
          if (dtmp) outO[o] = v + b0[coln] + bf2f(dtmp[o]);
          else      outO[o] = outO[o] + v + b0[coln];
        }
      }
    }
  }
}

// ---------------- scan: s_t = a*s + (1-a)*b ; cs = c*s ----------------
// abc layout: (m, 768) BF16, cols [0,256)=a (post-sigmoid), [256,512)=b,
// [512,768)=c (post-tanh)
__global__ void scanA_kernel(const u16* __restrict__ abc,
                             float* __restrict__ Asum, float* __restrict__ Usum) {
  int idx = blockIdx.x * blockDim.x + threadIdx.x;    // chunk*2048 + chain
  int chain = idx & (CHAINS - 1);
  int ch = idx >> 11;
  int bb = chain >> 8, n = chain & 255;
  const u16* base = abc + (size_t)(bb*Tt + ch*TC) * 768;
  float A = 1.f, U = 0.f;
  for (int t = 0; t < TC; ++t) {
    float a = bf2f(base[(size_t)t*768 + n]);
    float b = bf2f(base[(size_t)t*768 + 256 + n]);
    U = a*U + (1.f - a)*b;
    A *= a;
  }
  Asum[idx] = A; Usum[idx] = U;
}

__global__ void scanB_kernel(const float* __restrict__ Asum, const float* __restrict__ Usum,
                             float* __restrict__ Spre) {
  int chain = blockIdx.x * blockDim.x + threadIdx.x;  // 0..2047
  float s = 0.f;
  for (int ch = 0; ch < NCH; ++ch) {
    int i = (ch << 11) + chain;
    Spre[i] = s;
    s = Asum[i]*s + Usum[i];
  }
}

__global__ void scanC_kernel(const u16* __restrict__ abc, const float* __restrict__ Spre,
                             u16* __restrict__ cs) {
  int idx = blockIdx.x * blockDim.x + threadIdx.x;
  int chain = idx & (CHAINS - 1);
  int ch = idx >> 11;
  int bb = chain >> 8, n = chain & 255;
  const u16* base = abc + (size_t)(bb*Tt + ch*TC) * 768;
  u16* csb = cs + (size_t)(bb*Tt + ch*TC) * 256 + n;
  float s = Spre[idx];
  for (int t = 0; t < TC; ++t) {
    float a = bf2f(base[(size_t)t*768 + n]);
    float b = bf2f(base[(size_t)t*768 + 256 + n]);
    float c = bf2f(base[(size_t)t*768 + 512 + n]);
    s = a*s + (1.f - a)*b;
    csb[(size_t)t*256] = f2bf(c*s);
  }
}

extern "C" void kernel_launch(void* const* d_in, const int* in_sizes, int n_in,
                              void* d_out, int out_size, void* d_ws, size_t ws_size,
                              hipStream_t stream) {
  const float* x  = (const float*)d_in[0];
  const float* Wa = (const float*)d_in[1];
  const float* ba = (const float*)d_in[2];
  const float* Wb = (const float*)d_in[3];
  const float* bb = (const float*)d_in[4];
  const float* Wc = (const float*)d_in[5];
  const float* bc = (const float*)d_in[6];
  const float* Wd = (const float*)d_in[7];
  const float* bd = (const float*)d_in[8];
  const float* Wy = (const float*)d_in[9];
  const float* by = (const float*)d_in[10];
  float* out = (float*)d_out;
  char* ws = (char*)d_ws;

  // workspace layout (bytes)
  u16*  xb    = (u16*) (ws + 0);          // 33,554,432
  u16*  Wcomb = (u16*) (ws + 33554432);   //  3,670,016
  u16*  Wyt   = (u16*) (ws + 37224448);   //    524,288
  u16*  abcb  = (u16*) (ws + 37748736);   // 25,165,824 (bf16 abc)
  u16*  cs    = (u16*) (ws + 62914560);   //  8,388,608
  float* Asum = (float*)(ws + 71303168);  //    262,144
  float* Usum = (float*)(ws + 71565312);  //    262,144
  float* Spre = (float*)(ws + 71827456);  //    262,144
  u16*  dtmp  = (ws_size >= WS_NEED) ? (u16*)(ws + 72089600) : nullptr; // 33,554,432

  // 1) fused prep: x->bf16 + weight pack (one launch)
  prep_kernel<<<CVT_BLOCKS + PACK_BLOCKS, 256, 0, stream>>>(
      x, xb, Wa, Wb, Wc, Wd, Wy, Wcomb, Wyt);
  // 2) fused GEMM: abcb = act(x@[Wa|Wb|Wc]+bias) bf16, dtmp = x@Wd + bd (bf16)
  //    grid = (16384/256) * (1792/128) = 64*14 = 896 (div by 8)
  gemm_bt_kernel<0><<<896, 512, 0, stream>>>(
      xb, Wcomb, Dd, NCOMB/128, abcb, out, dtmp, ba, bb, bc, bd);
  // 3) chunked scan
  scanA_kernel<<<CHAINS*NCH/256, 256, 0, stream>>>(abcb, Asum, Usum);
  scanB_kernel<<<CHAINS/256, 256, 0, stream>>>(Asum, Usum, Spre);
  scanC_kernel<<<CHAINS*NCH/256, 256, 0, stream>>>(abcb, Spre, cs);
  // 4) out = cs @ Wy + by + dtmp   grid = 64*8 = 512 (div by 8)
  gemm_bt_kernel<2><<<512, 512, 0, stream>>>(
      cs, Wyt, Nn, Dd/128, nullptr, out, dtmp, by, nullptr, nullptr, nullptr);
}